// Round 1
// baseline (223.591 us; speedup 1.0000x reference)
//
#include <hip/hip_runtime.h>
#include <math.h>

#define N_RAYS 65536
#define NSTEP 128

__device__ __forceinline__ float fast_rcp(float x) { return __builtin_amdgcn_rcpf(x); }
__device__ __forceinline__ float sigmoidf_(float x) {
    return fast_rcp(1.0f + __expf(-x));
}

__global__ __launch_bounds__(256) void nerf_render_kernel(
    const float* __restrict__ rays_o, const float* __restrict__ rays_d,
    const float* __restrict__ cptr, const float* __restrict__ log_s,
    const float* __restrict__ amp, const float* __restrict__ Wc,
    const float* __restrict__ bc, float* __restrict__ out)
{
    int ray = blockIdx.x * blockDim.x + threadIdx.x;
    if (ray >= N_RAYS) return;

    // ---- load ray ----
    float ox = rays_o[ray*3+0], oy = rays_o[ray*3+1], oz = rays_o[ray*3+2];
    float dx = rays_d[ray*3+0], dy = rays_d[ray*3+1], dz = rays_d[ray*3+2];
    float inv_n = rsqrtf(dx*dx + dy*dy + dz*dz);
    dx *= inv_n; dy *= inv_n; dz *= inv_n;

    // ---- params (uniform; cached) ----
    float cx = cptr[0], cy = cptr[1], cz = cptr[2];
    float s  = __expf(log_s[0]);
    float inv2s2 = fast_rcp(2.0f * s * s);
    float ampv = amp[0];
    float w00 = Wc[0], w01 = Wc[1], w02 = Wc[2];
    float w10 = Wc[3], w11 = Wc[4], w12 = Wc[5];
    float w20 = Wc[6], w21 = Wc[7], w22 = Wc[8];
    float b0 = bc[0], b1 = bc[1], b2 = bc[2];

    // ---- near/far from AABB [-1,1] ----
    auto safe_inv = [](float d) {
        float sg = (d > 0.f) ? 1.f : ((d < 0.f) ? -1.f : 0.f);
        float sd = (fabsf(d) > 1e-8f) ? d : (sg * 1e-8f + 1e-12f);
        return 1.0f / sd;
    };
    float ixv = safe_inv(dx), iyv = safe_inv(dy), izv = safe_inv(dz);
    float t1x = (-1.f - ox) * ixv, t2x = (1.f - ox) * ixv;
    float t1y = (-1.f - oy) * iyv, t2y = (1.f - oy) * iyv;
    float t1z = (-1.f - oz) * izv, t2z = (1.f - oz) * izv;
    float near = fmaxf(fmaxf(fminf(t1x,t2x), fminf(t1y,t2y)), fminf(t1z,t2z));
    float far  = fminf(fminf(fmaxf(t1x,t2x), fmaxf(t1y,t2y)), fmaxf(t1z,t2z));
    near = fmaxf(near, 0.05f);
    far  = fmaxf(far, near + 1e-4f);

    float span = far - near;
    float step = span * (1.0f/127.0f);        // coarse z spacing
    float sample_dist = span * (1.0f/128.0f); // last delta

    // sigma at parametric z (clipped position)
    auto sigma_at = [&](float z) {
        float px = fminf(fmaxf(ox + dx*z, -1.f), 1.f);
        float py = fminf(fmaxf(oy + dy*z, -1.f), 1.f);
        float pz = fminf(fmaxf(oz + dz*z, -1.f), 1.f);
        float ax = px - cx, ay = py - cy, az = pz - cz;
        float d2 = ax*ax + ay*ay + az*az;
        return __expf(ampv - d2 * inv2s2);
    };

    // ---- pass 1: coarse chain -> weight-sum for pdf normalization ----
    float T = 1.f, wsum = 0.f;
    #pragma unroll 4
    for (int i = 0; i < NSTEP; i++) {
        float z = near + step * i;
        float sg = sigma_at(z);
        float delta = (i < NSTEP-1) ? step : sample_dist;
        float alpha = 1.f - __expf(-delta * sg);
        float w = alpha * T;
        if (i >= 1 && i <= 126) wsum += w + 1e-5f;
        T *= (1.f - alpha + 1e-15f);
    }
    float inv_wsum = fast_rcp(wsum); // wsum >= 126e-5, safe

    // ---- inverse-CDF generator state (segment k: [cdf_k, cdf_{k+1}), k=0..125) ----
    // pdf[k] uses coarse weight index k+1
    int   k = 0;
    float c_lo = 0.f, c_hi;
    float T2 = 1.f;
    {
        float a0 = 1.f - __expf(-step * sigma_at(near));
        T2 *= (1.f - a0 + 1e-15f);
        float a1 = 1.f - __expf(-step * sigma_at(near + step));
        float w1 = a1 * T2;
        T2 *= (1.f - a1 + 1e-15f);
        c_hi = (w1 + 1e-5f) * inv_wsum;
    }
    int i2 = 2;   // next coarse index in the T2 chain
    int jj = 0;   // next fine-sample index

    auto zmid = [&](int i) { return near + step * ((float)i + 0.5f); };

    auto nextB = [&]() {
        float u = ((float)jj + 0.5f) * (1.0f/128.0f);
        jj++;
        while (u >= c_hi && k < 125) {
            k++;
            c_lo = c_hi;
            float a = 1.f - __expf(-step * sigma_at(near + step * (float)i2));
            float w = a * T2;
            T2 *= (1.f - a + 1e-15f);
            i2++;
            c_hi = c_lo + (w + 1e-5f) * inv_wsum;
        }
        float z;
        if (u >= c_hi) {
            z = zmid(126);
        } else {
            float denom = c_hi - c_lo;
            if (denom < 1e-5f) denom = 1.f;
            float t = (u - c_lo) / denom;
            z = zmid(k) + t * (zmid(k+1) - zmid(k));
        }
        return z;
    };

    // ---- streaming merge of coarse grid (A) and importance samples (B),
    //      fused with fine compositing ----
    const float FLT_BIG = 3.402823e38f;
    int ma = 0, mb = 0;
    float za = near;          // z_a(0)
    float zb = nextB();

    auto popMin = [&]() {
        float v;
        if (ma < NSTEP && (mb >= NSTEP || za <= zb)) {
            v = za; ma++;
            za = (ma < NSTEP) ? (near + step * (float)ma) : FLT_BIG;
        } else {
            v = zb; mb++;
            zb = (mb < NSTEP) ? nextB() : FLT_BIG;
        }
        return v;
    };

    float T3 = 1.f, wacc = 0.f;
    float rr = 0.f, gg = 0.f, bb = 0.f;
    float cur = popMin();
    for (int t = 0; t < 2*NSTEP; t++) {
        float nxt = cur;
        if (t < 2*NSTEP - 1) nxt = popMin();
        float delta = (t < 2*NSTEP - 1) ? (nxt - cur) : sample_dist;

        float px = fminf(fmaxf(ox + dx*cur, -1.f), 1.f);
        float py = fminf(fmaxf(oy + dy*cur, -1.f), 1.f);
        float pz = fminf(fmaxf(oz + dz*cur, -1.f), 1.f);
        float ax = px - cx, ay = py - cy, az = pz - cz;
        float d2 = ax*ax + ay*ay + az*az;
        float sg = __expf(ampv - d2 * inv2s2);
        float alpha = 1.f - __expf(-delta * sg);
        float w = alpha * T3;

        float e0 = px*w00 + py*w10 + pz*w20 + b0;
        float e1 = px*w01 + py*w11 + pz*w21 + b1;
        float e2 = px*w02 + py*w12 + pz*w22 + b2;
        rr += w * sigmoidf_(e0);
        gg += w * sigmoidf_(e1);
        bb += w * sigmoidf_(e2);
        wacc += w;

        T3 *= (1.f - alpha + 1e-15f);
        cur = nxt;
    }

    float bg = 1.f - wacc;
    out[ray*3+0] = rr + bg;
    out[ray*3+1] = gg + bg;
    out[ray*3+2] = bb + bg;
}

extern "C" void kernel_launch(void* const* d_in, const int* in_sizes, int n_in,
                              void* d_out, int out_size, void* d_ws, size_t ws_size,
                              hipStream_t stream) {
    const float* rays_o = (const float*)d_in[0];
    const float* rays_d = (const float*)d_in[1];
    const float* c      = (const float*)d_in[2];
    const float* log_s  = (const float*)d_in[3];
    const float* amp    = (const float*)d_in[4];
    const float* Wc     = (const float*)d_in[5];
    const float* bc     = (const float*)d_in[6];
    float* out = (float*)d_out;

    dim3 block(256);
    dim3 grid((N_RAYS + 255) / 256);
    hipLaunchKernelGGL(nerf_render_kernel, grid, block, 0, stream,
                       rays_o, rays_d, c, log_s, amp, Wc, bc, out);
}

// Round 2
// 68.863 us; speedup vs baseline: 3.2469x; 3.2469x over previous
//
#include <hip/hip_runtime.h>
#include <math.h>

#define N_RAYS 65536

__device__ __forceinline__ float fast_rcp(float x){ return __builtin_amdgcn_rcpf(x); }
__device__ __forceinline__ float sigmoidf_(float x){ return fast_rcp(1.0f + __expf(-x)); }

// 64-lane inclusive scans
__device__ __forceinline__ float wave_scan_mul(float v, int lane) {
    #pragma unroll
    for (int d = 1; d < 64; d <<= 1) {
        float o = __shfl_up(v, d, 64);
        if (lane >= d) v *= o;
    }
    return v;
}
__device__ __forceinline__ float wave_scan_add(float v, int lane) {
    #pragma unroll
    for (int d = 1; d < 64; d <<= 1) {
        float o = __shfl_up(v, d, 64);
        if (lane >= d) v += o;
    }
    return v;
}
__device__ __forceinline__ float wave_reduce_add(float v) {
    #pragma unroll
    for (int d = 32; d >= 1; d >>= 1) v += __shfl_xor(v, d, 64);
    return v;
}

// count of elements of a[0..126] (sorted) that are <= u   (searchsorted right, n=127)
__device__ __forceinline__ int cdf_searchsorted(const float* a, float u) {
    int pos = 0;
    #pragma unroll
    for (int st = 64; st >= 1; st >>= 1) {
        if (a[pos + st - 1] <= u) pos += st;
    }
    return pos; // in [0,127]
}
// count of elements of a[0..127] (sorted) that are < z  (lower bound, n=128)
__device__ __forceinline__ int count_less(const float* a, float z) {
    int pos = 0;
    #pragma unroll
    for (int st = 64; st >= 1; st >>= 1) {
        if (a[pos + st - 1] < z) pos += st;
    }
    if (pos < 128 && a[pos] < z) pos++;
    return pos; // in [0,128]
}
// count of elements of a[0..127] (sorted) that are <= z (upper bound, n=128)
__device__ __forceinline__ int count_le(const float* a, float z) {
    int pos = 0;
    #pragma unroll
    for (int st = 64; st >= 1; st >>= 1) {
        if (a[pos + st - 1] <= z) pos += st;
    }
    if (pos < 128 && a[pos] <= z) pos++;
    return pos; // in [0,128]
}

__global__ __launch_bounds__(256) void nerf_wave_kernel(
    const float* __restrict__ rays_o, const float* __restrict__ rays_d,
    const float* __restrict__ cptr, const float* __restrict__ log_s,
    const float* __restrict__ amp, const float* __restrict__ Wc,
    const float* __restrict__ bc, float* __restrict__ out)
{
    const int lane = (int)(threadIdx.x & 63u);
    const int wv   = (int)(threadIdx.x >> 6);
    const int ray  = (int)(blockIdx.x << 2) + wv;

    __shared__ float s_cdf[4][128];
    __shared__ float s_fine[4][128];
    __shared__ float s_coarse[4][128];
    __shared__ float s_zall[4][256];

    float* __restrict__ cdf  = s_cdf[wv];
    float* __restrict__ fz   = s_fine[wv];
    float* __restrict__ czz  = s_coarse[wv];
    float* __restrict__ zall = s_zall[wv];

    // ---- ray + params (wave-uniform loads, broadcast in cache) ----
    float ox = rays_o[ray*3+0], oy = rays_o[ray*3+1], oz = rays_o[ray*3+2];
    float dx = rays_d[ray*3+0], dy = rays_d[ray*3+1], dz = rays_d[ray*3+2];
    float inv_n = rsqrtf(dx*dx + dy*dy + dz*dz);
    dx *= inv_n; dy *= inv_n; dz *= inv_n;

    float ccx = cptr[0], ccy = cptr[1], ccz = cptr[2];
    float sv  = __expf(log_s[0]);
    float inv2s2 = fast_rcp(2.0f * sv * sv);
    float ampv = amp[0];
    float w00 = Wc[0], w01 = Wc[1], w02 = Wc[2];
    float w10 = Wc[3], w11 = Wc[4], w12 = Wc[5];
    float w20 = Wc[6], w21 = Wc[7], w22 = Wc[8];
    float b0 = bc[0], b1 = bc[1], b2 = bc[2];

    // ---- near/far ----
    auto safe_inv = [](float d) {
        float sg = (d > 0.f) ? 1.f : ((d < 0.f) ? -1.f : 0.f);
        float sd = (fabsf(d) > 1e-8f) ? d : (sg * 1e-8f + 1e-12f);
        return 1.0f / sd;
    };
    float ixv = safe_inv(dx), iyv = safe_inv(dy), izv = safe_inv(dz);
    float t1x = (-1.f - ox) * ixv, t2x = (1.f - ox) * ixv;
    float t1y = (-1.f - oy) * iyv, t2y = (1.f - oy) * iyv;
    float t1z = (-1.f - oz) * izv, t2z = (1.f - oz) * izv;
    float nearz = fmaxf(fmaxf(fminf(t1x,t2x), fminf(t1y,t2y)), fminf(t1z,t2z));
    float farz  = fminf(fminf(fmaxf(t1x,t2x), fmaxf(t1y,t2y)), fmaxf(t1z,t2z));
    nearz = fmaxf(nearz, 0.05f);
    farz  = fmaxf(farz, nearz + 1e-4f);

    float span = farz - nearz;
    float step = span * (1.0f/127.0f);
    float sample_dist = span * (1.0f/128.0f);

    auto sigma_at_clip = [&](float z, float& px, float& py, float& pz) {
        px = fminf(fmaxf(ox + dx*z, -1.f), 1.f);
        py = fminf(fmaxf(oy + dy*z, -1.f), 1.f);
        pz = fminf(fmaxf(oz + dz*z, -1.f), 1.f);
        float ax = px - ccx, ay = py - ccy, az = pz - ccz;
        float d2 = ax*ax + ay*ay + az*az;
        return __expf(ampv - d2 * inv2s2);
    };

    // ==== phase 1: coarse chain (2 samples/lane), scans for T and CDF ====
    int i0 = 2*lane, i1 = 2*lane + 1;
    float z0 = nearz + step * (float)i0;
    float z1 = nearz + step * (float)i1;
    czz[i0] = z0; czz[i1] = z1;

    float px_, py_, pz_;
    float sg0 = sigma_at_clip(z0, px_, py_, pz_);
    float sg1 = sigma_at_clip(z1, px_, py_, pz_);
    float d0 = step;
    float d1 = (i1 == 127) ? sample_dist : step;
    float a0 = 1.f - __expf(-d0 * sg0);
    float a1 = 1.f - __expf(-d1 * sg1);
    float g0 = 1.f - a0 + 1e-15f;
    float g1 = 1.f - a1 + 1e-15f;

    // transmittance product scan
    float tot = g0 * g1;
    float incl = wave_scan_mul(tot, lane);
    float excl = __shfl_up(incl, 1, 64);
    if (lane == 0) excl = 1.f;
    float wgt0 = a0 * excl;
    float wgt1 = a1 * (excl * g0);

    // cdf sum scan over h_i = (1<=i<=126) ? w_i + 1e-5 : 0
    float h0 = (i0 >= 1) ? (wgt0 + 1e-5f) : 0.f;           // i0 in [0,126]
    float h1 = (i1 <= 126) ? (wgt1 + 1e-5f) : 0.f;         // i1 in [1,127]
    float hp = h0 + h1;
    float Hincl = wave_scan_add(hp, lane);
    float Hexcl = __shfl_up(Hincl, 1, 64);
    if (lane == 0) Hexcl = 0.f;
    float wsum = __shfl(Hincl, 63, 64);
    float inv_wsum = 1.0f / wsum;                          // wsum >= 126e-5

    cdf[i0] = (Hexcl + h0) * inv_wsum;                     // cdf[0] = 0 exactly
    if (i1 <= 126) cdf[i1] = Hincl * inv_wsum;

    __syncthreads();

    // ==== phase 2: fine samples via inverse CDF (2 u's per lane) ====
    #pragma unroll
    for (int q = 0; q < 2; q++) {
        int j = lane + 64*q;
        float u = ((float)j + 0.5f) * (1.0f/128.0f);
        int ind = cdf_searchsorted(cdf, u);
        int below = max(ind - 1, 0);
        int above = min(ind, 126);
        float cb = cdf[below], ca = cdf[above];
        float zb = nearz + step * ((float)below + 0.5f);
        float za = nearz + step * ((float)above + 0.5f);
        float denom = ca - cb;
        if (denom < 1e-5f) denom = 1.f;
        float tt = (u - cb) / denom;
        fz[j] = zb + tt * (za - zb);
    }

    __syncthreads();

    // ==== phase 3: merge by rank (permutation: coarse strict-<, fine non-strict-<=) ====
    {
        float zc0 = czz[i0], zc1 = czz[i1];
        zall[i0 + count_less(fz, zc0)] = zc0;
        zall[i1 + count_less(fz, zc1)] = zc1;
        #pragma unroll
        for (int q = 0; q < 2; q++) {
            int j = lane + 64*q;
            float zf = fz[j];
            zall[j + count_le(czz, zf)] = zf;
        }
    }

    __syncthreads();

    // ==== phase 4: fine compositing over 256 merged samples (4/lane) ====
    float zt[5];
    #pragma unroll
    for (int q = 0; q < 4; q++) zt[q] = zall[4*lane + q];
    zt[4] = (lane < 63) ? zall[4*lane + 4] : zt[3];

    float al[4], gg_[4];
    float pxs[4], pys[4], pzs[4];
    #pragma unroll
    for (int q = 0; q < 4; q++) {
        float sg = sigma_at_clip(zt[q], pxs[q], pys[q], pzs[q]);
        float delta = (q < 3) ? (zt[q+1] - zt[q])
                              : ((lane < 63) ? (zt[4] - zt[3]) : sample_dist);
        al[q] = 1.f - __expf(-delta * sg);
        gg_[q] = 1.f - al[q] + 1e-15f;
    }
    float pre1 = gg_[0];
    float pre2 = pre1 * gg_[1];
    float pre3 = pre2 * gg_[2];
    float tot4 = pre3 * gg_[3];
    float incl4 = wave_scan_mul(tot4, lane);
    float excl4 = __shfl_up(incl4, 1, 64);
    if (lane == 0) excl4 = 1.f;

    float Tq[4] = { excl4, excl4*pre1, excl4*pre2, excl4*pre3 };
    float rr = 0.f, gcol = 0.f, bcol = 0.f, wacc = 0.f;
    #pragma unroll
    for (int q = 0; q < 4; q++) {
        float w = al[q] * Tq[q];
        float e0 = pxs[q]*w00 + pys[q]*w10 + pzs[q]*w20 + b0;
        float e1 = pxs[q]*w01 + pys[q]*w11 + pzs[q]*w21 + b1;
        float e2 = pxs[q]*w02 + pys[q]*w12 + pzs[q]*w22 + b2;
        rr   += w * sigmoidf_(e0);
        gcol += w * sigmoidf_(e1);
        bcol += w * sigmoidf_(e2);
        wacc += w;
    }
    rr   = wave_reduce_add(rr);
    gcol = wave_reduce_add(gcol);
    bcol = wave_reduce_add(bcol);
    wacc = wave_reduce_add(wacc);

    if (lane == 0) {
        float bg = 1.f - wacc;
        out[ray*3+0] = rr + bg;
        out[ray*3+1] = gcol + bg;
        out[ray*3+2] = bcol + bg;
    }
}

extern "C" void kernel_launch(void* const* d_in, const int* in_sizes, int n_in,
                              void* d_out, int out_size, void* d_ws, size_t ws_size,
                              hipStream_t stream) {
    const float* rays_o = (const float*)d_in[0];
    const float* rays_d = (const float*)d_in[1];
    const float* c      = (const float*)d_in[2];
    const float* log_s  = (const float*)d_in[3];
    const float* amp    = (const float*)d_in[4];
    const float* Wc     = (const float*)d_in[5];
    const float* bc     = (const float*)d_in[6];
    float* out = (float*)d_out;

    dim3 block(256);
    dim3 grid(N_RAYS / 4); // 4 rays (waves) per block
    hipLaunchKernelGGL(nerf_wave_kernel, grid, block, 0, stream,
                       rays_o, rays_d, c, log_s, amp, Wc, bc, out);
}